// Round 16
// baseline (36.951 us; speedup 1.0000x reference)
//
#include <hip/hip_runtime.h>
#include <cmath>

// Bokeh render, gather form:
// out[b,c,y,x] = sum_{dy,dx} w * img[b,c,y-dy,x-dx] / sum w
// w = sigmoid(8*(r_src - dist)) / max(pi*r_src^2,1);  r = |defocus| in [0,4).
// Window mask dropped; additionally taps with d^2 >= 25 dropped entirely
// (they require r>=3 in the ref window, where w <= sigma(-8)/(9pi) ~ 1.2e-5;
// total output shift <= 1.4e-4). OOB sources: J=1e30,H=0 -> w ~= 0.
//
// R16 = R15 (16.8us; pk_fma accumulation, J|H fold, 2 dy-groups) +
//  (1) tap narrowing 81->69: rows |dyo|=4 keep |dxo|<=2, |dyo|=3 drop
//      |dxo|=4, via tap_rows<XLO,XHI> under wave-uniform branch.
//  (2) 2-tile double-buffer: grid 8x32x1, each block does b=0 then b=1
//      for its (x,y) tile. T1's global loads issue BEFORE compute(T0)
//      (regs), LDS writes after -> staging HBM latency hides under
//      compute. No asm fences (R8 scratch lesson). Cost: 1 blk/CU ->
//      2 waves/SIMD in compute phases (R7vR10: ~ +1.2us penalty), gain:
//      ~2-2.5us staging exposure removed.

#define HH 512
#define WW 512
#define TW 64                     // tile width (16 quads)
#define TH 16                     // tile height
#define HALO 4
#define SROWS (TH + 2 * HALO)     // 24
#define LW 72                     // 4 + 64 + 4 dwords per row
#define NENT (SROWS * LW)         // 1728 staged entries per tile

typedef float v2f __attribute__((ext_vector_type(2)));

__device__ __forceinline__ unsigned rtne_hi(float v) {
  // bf16 round-to-nearest-even, result in HIGH 16 bits (low 16 zero).
  unsigned u = __float_as_uint(v);
  u = u + 0x7FFFu + ((u >> 16) & 1u);
  return u & 0xFFFF0000u;
}

template <int XLO, int XHI>
__device__ __forceinline__ void tap_rows(const float* __restrict__ fdr,
                                         const float* __restrict__ Jv,
                                         const float* __restrict__ Hv,
                                         const v2f* __restrict__ C01,
                                         const v2f* __restrict__ Z1,
                                         v2f (&a01)[4], v2f (&a2w)[4]) {
  #pragma unroll
  for (int k = 0; k < 4; ++k) {
    #pragma unroll
    for (int xi = XLO; xi < XHI; ++xi) {
      const int j = k + xi;                      // compile-time
      float tden = fmaf(Hv[j], fdr[xi], Jv[j]);  // J + e^{-8r}J e^{8d}
      float w = __builtin_amdgcn_rcpf(tden);     // = Iv * sigmoid
      v2f wp = {w, w};
      a01[k] = __builtin_elementwise_fma(wp, C01[j], a01[k]);
      a2w[k] = __builtin_elementwise_fma(wp, Z1[j], a2w[k]);
    }
  }
}

__global__ __launch_bounds__(512, 4) void bokeh_gather(
    const float* __restrict__ img,
    const float* __restrict__ def,
    float* __restrict__ out)
{
  __shared__ __align__(16) unsigned sX[2][SROWS][LW];  // J(hi)|H(lo) bf16
  __shared__ __align__(16) unsigned sY[2][SROWS][LW];  // c0(hi)|c1(lo) bf16
  __shared__ __align__(16) unsigned sZ[2][SROWS][LW];  // c2 trunc f32
  __shared__ float sFd[9][12];                         // exp(8*dist(dy,dx))
  __shared__ __align__(16) float pbuf[256][20];        // group-1 partials

  const int tid = threadIdx.x;
  const int s   = tid >> 8;      // dy-group: 0 -> dy 0..4, 1 -> dy 5..8
  const int t   = tid & 255;
  const int tx  = t & 15;        // 16 lanes * 4 px = 64 cols
  const int ty  = t >> 4;        // 16 rows
  const int bx = blockIdx.x * TW;
  const int by = blockIdx.y * TH;

  if (tid < 81) {
    int dyi = tid / 9, dxi = tid - dyi * 9;
    int dyo = dyi - 4, dxo = dxi - 4;
    float d2 = (float)(dyo * dyo + dxo * dxo);
    sFd[dyi][dxi] = __expf(8.0f * sqrtf(d2));
  }

  // ---- stage T0 (b=0) into buf 0 (plain: load+process+write) ----
  {
    const float* dpt = def;
    const float* ipt = img;
    for (int idx = tid; idx < NENT; idx += 512) {
      int ly = idx / LW;
      int lx = idx - ly * LW;
      int sy = by - HALO + ly;
      int sx = bx - HALO + lx;
      unsigned X, Y = 0u, Z = 0u;
      if ((unsigned)sy < (unsigned)HH && (unsigned)sx < (unsigned)WW) {
        int o = sy * WW + sx;
        float r = fabsf(dpt[o]);
        float J  = fmaxf(3.14159265358979f * r * r, 1.0f);
        float Hv = __expf(-8.0f * r) * J;
        X = rtne_hi(J) | (rtne_hi(Hv) >> 16);
        Y = rtne_hi(ipt[o]) | (rtne_hi(ipt[o + HH * WW]) >> 16);
        Z = __float_as_uint(ipt[o + 2 * HH * WW]) & 0xFFFF0000u;
      } else {
        X = rtne_hi(1e30f);
      }
      sX[0][ly][lx] = X;
      sY[0][ly][lx] = Y;
      sZ[0][ly][lx] = Z;
    }
  }
  __syncthreads();

  // ---- issue T1 (b=1) global loads into registers (overlap w/ compute0) --
  float r1v[4], c0v[4], c1v[4], c2v[4];
  {
    const float* dpt = def + HH * WW;
    const float* ipt = img + 3 * HH * WW;
    #pragma unroll
    for (int i = 0; i < 4; ++i) {
      int idx = tid + 512 * i;
      int ly = idx / LW;
      int lx = idx - ly * LW;
      int sy = by - HALO + ly;
      int sx = bx - HALO + lx;
      bool inb = (idx < NENT) &&
                 (unsigned)sy < (unsigned)HH && (unsigned)sx < (unsigned)WW;
      int o = sy * WW + sx;
      r1v[i] = inb ? dpt[o] : -1.0f;             // r<0 flags OOB
      c0v[i] = inb ? ipt[o] : 0.0f;
      c1v[i] = inb ? ipt[o + HH * WW] : 0.0f;
      c2v[i] = inb ? ipt[o + 2 * HH * WW] : 0.0f;
    }
  }

  const int col0 = 4 * tx;
  const int dy0 = s ? 5 : 0;
  const int dy1 = s ? 9 : 5;

  // ---- compute helper (q = buffer index) ----
  auto compute_tile = [&](int q, v2f (&a01)[4], v2f (&a2w)[4]) {
    #pragma unroll 1
    for (int dy = dy0; dy < dy1; ++dy) {
      const int sr = ty + dy;
      float fdr[9];
      #pragma unroll
      for (int x = 0; x < 9; ++x) fdr[x] = sFd[dy][x];

      unsigned Xv[12], Yv[12], Zv[12];
      #pragma unroll
      for (int qq = 0; qq < 3; ++qq) {
        *(uint4*)&Xv[4 * qq] = *(const uint4*)(&sX[q][sr][col0] + 4 * qq);
        *(uint4*)&Yv[4 * qq] = *(const uint4*)(&sY[q][sr][col0] + 4 * qq);
        *(uint4*)&Zv[4 * qq] = *(const uint4*)(&sZ[q][sr][col0] + 4 * qq);
      }
      float Jv[12], Hv[12];
      v2f C01[12], Z1[12];
      #pragma unroll
      for (int j = 0; j < 12; ++j) {
        Jv[j] = __uint_as_float(Xv[j] & 0xFFFF0000u);
        Hv[j] = __uint_as_float(Xv[j] << 16);
        C01[j] = (v2f){__uint_as_float(Yv[j] & 0xFFFF0000u),
                       __uint_as_float(Yv[j] << 16)};
        Z1[j]  = (v2f){__uint_as_float(Zv[j]), 1.0f};
      }

      const int ady = dy < 4 ? 4 - dy : dy - 4;   // wave-uniform
      if (ady == 4)      tap_rows<2, 7>(fdr, Jv, Hv, C01, Z1, a01, a2w);
      else if (ady == 3) tap_rows<1, 8>(fdr, Jv, Hv, C01, Z1, a01, a2w);
      else               tap_rows<0, 9>(fdr, Jv, Hv, C01, Z1, a01, a2w);
    }
  };

  auto combine_write = [&](int b, v2f (&a01)[4], v2f (&a2w)[4]) {
    if (s == 1) {
      *(float4*)&pbuf[t][0]  = make_float4(a2w[0].y, a2w[1].y, a2w[2].y, a2w[3].y);
      *(float4*)&pbuf[t][4]  = make_float4(a01[0].x, a01[1].x, a01[2].x, a01[3].x);
      *(float4*)&pbuf[t][8]  = make_float4(a01[0].y, a01[1].y, a01[2].y, a01[3].y);
      *(float4*)&pbuf[t][12] = make_float4(a2w[0].x, a2w[1].x, a2w[2].x, a2w[3].x);
    }
    __syncthreads();
    if (s == 0) {
      float4 v0 = *(const float4*)&pbuf[t][0];
      float4 v1 = *(const float4*)&pbuf[t][4];
      float4 v2 = *(const float4*)&pbuf[t][8];
      float4 v3 = *(const float4*)&pbuf[t][12];
      float wsum[4] = {a2w[0].y + v0.x, a2w[1].y + v0.y,
                       a2w[2].y + v0.z, a2w[3].y + v0.w};
      float ac0[4]  = {a01[0].x + v1.x, a01[1].x + v1.y,
                       a01[2].x + v1.z, a01[3].x + v1.w};
      float ac1[4]  = {a01[0].y + v2.x, a01[1].y + v2.y,
                       a01[2].y + v2.z, a01[3].y + v2.w};
      float ac2[4]  = {a2w[0].x + v3.x, a2w[1].x + v3.y,
                       a2w[2].x + v3.z, a2w[3].x + v3.w};
      const int oy = by + ty;
      const int ox = bx + col0;
      float rw[4];
      #pragma unroll
      for (int k = 0; k < 4; ++k) rw[k] = __builtin_amdgcn_rcpf(wsum[k]);
      float* op0 = out + ((b * 3 + 0) * HH + oy) * WW + ox;
      float* op1 = out + ((b * 3 + 1) * HH + oy) * WW + ox;
      float* op2 = out + ((b * 3 + 2) * HH + oy) * WW + ox;
      float4 o0, o1, o2;
      o0.x = ac0[0]*rw[0]; o0.y = ac0[1]*rw[1]; o0.z = ac0[2]*rw[2]; o0.w = ac0[3]*rw[3];
      o1.x = ac1[0]*rw[0]; o1.y = ac1[1]*rw[1]; o1.z = ac1[2]*rw[2]; o1.w = ac1[3]*rw[3];
      o2.x = ac2[0]*rw[0]; o2.y = ac2[1]*rw[1]; o2.z = ac2[2]*rw[2]; o2.w = ac2[3]*rw[3];
      *(float4*)op0 = o0;
      *(float4*)op1 = o1;
      *(float4*)op2 = o2;
    }
  };

  // ---- phase 0: compute T0 (buf0); then write staged T1 -> buf1 ----
  v2f a01[4] = {{0.f,0.f},{0.f,0.f},{0.f,0.f},{0.f,0.f}};
  v2f a2w[4] = {{0.f,0.f},{0.f,0.f},{0.f,0.f},{0.f,0.f}};
  compute_tile(0, a01, a2w);

  // process + write T1 staged registers into buf1
  #pragma unroll
  for (int i = 0; i < 4; ++i) {
    int idx = tid + 512 * i;
    if (idx < NENT) {
      int ly = idx / LW;
      int lx = idx - ly * LW;
      unsigned X, Y = 0u, Z = 0u;
      if (r1v[i] >= 0.0f) {
        float r = r1v[i];                        // already >= 0 in-bounds
        float J  = fmaxf(3.14159265358979f * r * r, 1.0f);
        float Hv = __expf(-8.0f * r) * J;
        X = rtne_hi(J) | (rtne_hi(Hv) >> 16);
        Y = rtne_hi(c0v[i]) | (rtne_hi(c1v[i]) >> 16);
        Z = __float_as_uint(c2v[i]) & 0xFFFF0000u;
      } else {
        X = rtne_hi(1e30f);
      }
      sX[1][ly][lx] = X;
      sY[1][ly][lx] = Y;
      sZ[1][ly][lx] = Z;
    }
  }

  combine_write(0, a01, a2w);   // has its own barrier before s==0 reads
  __syncthreads();              // pbuf free + buf1 ready for all

  // ---- phase 1: compute T1 (buf1) ----
  #pragma unroll
  for (int k = 0; k < 4; ++k) { a01[k] = (v2f){0.f,0.f}; a2w[k] = (v2f){0.f,0.f}; }
  compute_tile(1, a01, a2w);
  combine_write(1, a01, a2w);
}

extern "C" void kernel_launch(void* const* d_in, const int* in_sizes, int n_in,
                              void* d_out, int out_size, void* d_ws, size_t ws_size,
                              hipStream_t stream) {
  const float* img = (const float*)d_in[0];   // (2,3,512,512) f32
  const float* def = (const float*)d_in[1];   // (2,1,512,512) f32
  float* out = (float*)d_out;                 // (2,3,512,512) f32

  dim3 grid(WW / TW, HH / TH, 1);             // 8 x 32 = 256 blocks = 1/CU
  dim3 block(512);
  hipLaunchKernelGGL(bokeh_gather, grid, block, 0, stream, img, def, out);
}

// Round 17
// 22.908 us; speedup vs baseline: 1.6130x; 1.6130x over previous
//
#include <hip/hip_runtime.h>
#include <cmath>

// Bokeh render, gather form:
// out[b,c,y,x] = sum_{dy,dx} w * img[b,c,y-dy,x-dx] / sum w
// w = sigmoid(8*(r_src - dist)) / max(pi*r_src^2,1);  r = |defocus| in [0,4).
// Window mask dropped (outside-window w <= sigma(-8): output shift <2e-5).
// Taps with d^2 >= 25 dropped entirely: in the ref window they require
// r >= 3, where w <= sigma(-8)/(9pi) ~ 1.2e-5 -> total shift <= 1.4e-4
// (empirically confirmed R16: absmax unchanged). OOB: J=1e30,H=0 -> w ~= 0.
//
// R17 = R15 (16.8us, session best) + tap narrowing ONLY. R16 bundled the
// narrowing with a 2-tile double-buffer that spilled (WRITE 36MB scratch,
// VALUBusy 19%, 1 blk/CU) -> 37us; levers confounded. This round unbundles:
// identical R15 structure (grid 8x32x2 = 2 blk/CU -> 4 waves/SIMD,
// 2 dy-groups x 256thr, bf16 3-array LDS, pk_fma accum, J|H fold), inner
// loop narrowed via tap_rows<XLO,XHI> under a wave-uniform ady branch:
// 81 -> 69 taps (-15% tap VALU).

#define HH 512
#define WW 512
#define NB 2
#define TW 64                     // tile width (16 quads, zero waste)
#define TH 16                     // tile height
#define HALO 4
#define SROWS (TH + 2 * HALO)     // 24
#define LW 72                     // 4 + 64 + 4 = exactly 72 dwords/row

typedef float v2f __attribute__((ext_vector_type(2)));

__device__ __forceinline__ unsigned rtne_hi(float v) {
  // bf16 round-to-nearest-even, result in HIGH 16 bits (low 16 zero).
  unsigned u = __float_as_uint(v);
  u = u + 0x7FFFu + ((u >> 16) & 1u);
  return u & 0xFFFF0000u;
}

template <int XLO, int XHI>
__device__ __forceinline__ void tap_rows(const float* __restrict__ fdr,
                                         const float* __restrict__ Jv,
                                         const float* __restrict__ Hv,
                                         const v2f* __restrict__ C01,
                                         const v2f* __restrict__ Z1,
                                         v2f (&a01)[4], v2f (&a2w)[4]) {
  #pragma unroll
  for (int k = 0; k < 4; ++k) {
    #pragma unroll
    for (int xi = XLO; xi < XHI; ++xi) {
      const int j = k + xi;                      // compile-time
      float tden = fmaf(Hv[j], fdr[xi], Jv[j]);  // J + e^{-8r}J e^{8d}
      float w = __builtin_amdgcn_rcpf(tden);     // = Iv * sigmoid
      v2f wp = {w, w};
      a01[k] = __builtin_elementwise_fma(wp, C01[j], a01[k]);
      a2w[k] = __builtin_elementwise_fma(wp, Z1[j], a2w[k]);
    }
  }
}

__global__ __launch_bounds__(512, 4) void bokeh_gather(
    const float* __restrict__ img,
    const float* __restrict__ def,
    float* __restrict__ out)
{
  __shared__ __align__(16) unsigned sX[SROWS][LW];  // J(hi) | H(lo)   bf16
  __shared__ __align__(16) unsigned sY[SROWS][LW];  // c0(hi) | c1(lo) bf16
  __shared__ __align__(16) unsigned sZ[SROWS][LW];  // c2 truncated f32
  __shared__ float sFd[9][12];                      // exp(8*dist(dy,dx))
  __shared__ __align__(16) float pbuf[256][20];     // group-1 partials

  const int tid = threadIdx.x;
  const int s   = tid >> 8;      // dy-group: 0 -> dy 0..4, 1 -> dy 5..8
  const int t   = tid & 255;
  const int tx  = t & 15;        // 16 lanes * 4 px = 64 cols
  const int ty  = t >> 4;        // 16 rows
  const int bx = blockIdx.x * TW;
  const int by = blockIdx.y * TH;
  const int b  = blockIdx.z;

  if (tid < 81) {
    int dyi = tid / 9, dxi = tid - dyi * 9;
    int dyo = dyi - 4, dxo = dxi - 4;
    float d2 = (float)(dyo * dyo + dxo * dxo);
    sFd[dyi][dxi] = __expf(8.0f * sqrtf(d2));
  }

  const float* dpt = def + b * (HH * WW);
  const float* ipt = img + b * (3 * HH * WW);

  // Stage halo'd tile: 24 rows x 72 cols = 1728 entries / 512 thr.
  for (int idx = tid; idx < SROWS * LW; idx += 512) {
    int ly = idx / LW;
    int lx = idx - ly * LW;
    int sy = by - HALO + ly;
    int sx = bx - HALO + lx;
    unsigned X, Y = 0u, Z = 0u;
    if ((unsigned)sy < (unsigned)HH && (unsigned)sx < (unsigned)WW) {
      int o = sy * WW + sx;
      float r = fabsf(dpt[o]);
      float J  = fmaxf(3.14159265358979f * r * r, 1.0f);
      float Hv = __expf(-8.0f * r) * J;
      X = rtne_hi(J) | (rtne_hi(Hv) >> 16);
      Y = rtne_hi(ipt[o]) | (rtne_hi(ipt[o + HH * WW]) >> 16);
      Z = __float_as_uint(ipt[o + 2 * HH * WW]) & 0xFFFF0000u;
    } else {
      X = rtne_hi(1e30f);        // J huge, H = 0 -> w ~= 1e-30, channels 0
    }
    sX[ly][lx] = X;
    sY[ly][lx] = Y;
    sZ[ly][lx] = Z;
  }
  __syncthreads();

  v2f a01[4] = {{0.f,0.f},{0.f,0.f},{0.f,0.f},{0.f,0.f}};  // (ac0, ac1)
  v2f a2w[4] = {{0.f,0.f},{0.f,0.f},{0.f,0.f},{0.f,0.f}};  // (ac2, wsum)

  const int col0 = 4 * tx;       // window start col (16B aligned)
  const int dy0 = s ? 5 : 0;
  const int dy1 = s ? 9 : 5;

  #pragma unroll 1
  for (int dy = dy0; dy < dy1; ++dy) {
    const int sr = ty + dy;
    float fdr[9];
    #pragma unroll
    for (int x = 0; x < 9; ++x) fdr[x] = sFd[dy][x];

    unsigned Xv[12], Yv[12], Zv[12];
    #pragma unroll
    for (int q = 0; q < 3; ++q) {
      *(uint4*)&Xv[4 * q] = *(const uint4*)(&sX[sr][col0] + 4 * q);
      *(uint4*)&Yv[4 * q] = *(const uint4*)(&sY[sr][col0] + 4 * q);
      *(uint4*)&Zv[4 * q] = *(const uint4*)(&sZ[sr][col0] + 4 * q);
    }
    float Jv[12], Hv[12];
    v2f C01[12], Z1[12];
    #pragma unroll
    for (int j = 0; j < 12; ++j) {
      Jv[j] = __uint_as_float(Xv[j] & 0xFFFF0000u);
      Hv[j] = __uint_as_float(Xv[j] << 16);
      C01[j] = (v2f){__uint_as_float(Yv[j] & 0xFFFF0000u),
                     __uint_as_float(Yv[j] << 16)};
      Z1[j]  = (v2f){__uint_as_float(Zv[j]), 1.0f};
    }

    const int ady = dy < 4 ? 4 - dy : dy - 4;   // wave-uniform
    if (ady == 4)      tap_rows<2, 7>(fdr, Jv, Hv, C01, Z1, a01, a2w);
    else if (ady == 3) tap_rows<1, 8>(fdr, Jv, Hv, C01, Z1, a01, a2w);
    else               tap_rows<0, 9>(fdr, Jv, Hv, C01, Z1, a01, a2w);
  }

  // Combine dy-halves: group 1 publishes, group 0 reduces + stores.
  if (s == 1) {
    *(float4*)&pbuf[t][0]  = make_float4(a2w[0].y, a2w[1].y, a2w[2].y, a2w[3].y);
    *(float4*)&pbuf[t][4]  = make_float4(a01[0].x, a01[1].x, a01[2].x, a01[3].x);
    *(float4*)&pbuf[t][8]  = make_float4(a01[0].y, a01[1].y, a01[2].y, a01[3].y);
    *(float4*)&pbuf[t][12] = make_float4(a2w[0].x, a2w[1].x, a2w[2].x, a2w[3].x);
  }
  __syncthreads();
  if (s == 0) {
    float4 v0 = *(const float4*)&pbuf[t][0];
    float4 v1 = *(const float4*)&pbuf[t][4];
    float4 v2 = *(const float4*)&pbuf[t][8];
    float4 v3 = *(const float4*)&pbuf[t][12];
    float wsum[4] = {a2w[0].y + v0.x, a2w[1].y + v0.y,
                     a2w[2].y + v0.z, a2w[3].y + v0.w};
    float ac0[4]  = {a01[0].x + v1.x, a01[1].x + v1.y,
                     a01[2].x + v1.z, a01[3].x + v1.w};
    float ac1[4]  = {a01[0].y + v2.x, a01[1].y + v2.y,
                     a01[2].y + v2.z, a01[3].y + v2.w};
    float ac2[4]  = {a2w[0].x + v3.x, a2w[1].x + v3.y,
                     a2w[2].x + v3.z, a2w[3].x + v3.w};

    const int oy = by + ty;
    const int ox = bx + col0;
    float rw[4];
    #pragma unroll
    for (int k = 0; k < 4; ++k) rw[k] = __builtin_amdgcn_rcpf(wsum[k]);

    float* op0 = out + ((b * 3 + 0) * HH + oy) * WW + ox;
    float* op1 = out + ((b * 3 + 1) * HH + oy) * WW + ox;
    float* op2 = out + ((b * 3 + 2) * HH + oy) * WW + ox;
    float4 o0, o1, o2;
    o0.x = ac0[0] * rw[0]; o0.y = ac0[1] * rw[1]; o0.z = ac0[2] * rw[2]; o0.w = ac0[3] * rw[3];
    o1.x = ac1[0] * rw[0]; o1.y = ac1[1] * rw[1]; o1.z = ac1[2] * rw[2]; o1.w = ac1[3] * rw[3];
    o2.x = ac2[0] * rw[0]; o2.y = ac2[1] * rw[1]; o2.z = ac2[2] * rw[2]; o2.w = ac2[3] * rw[3];
    *(float4*)op0 = o0;
    *(float4*)op1 = o1;
    *(float4*)op2 = o2;
  }
}

extern "C" void kernel_launch(void* const* d_in, const int* in_sizes, int n_in,
                              void* d_out, int out_size, void* d_ws, size_t ws_size,
                              hipStream_t stream) {
  const float* img = (const float*)d_in[0];   // (2,3,512,512) f32
  const float* def = (const float*)d_in[1];   // (2,1,512,512) f32
  float* out = (float*)d_out;                 // (2,3,512,512) f32

  dim3 grid(WW / TW, HH / TH, NB);            // 8 x 32 x 2 = 512 blocks = 2/CU
  dim3 block(512);
  hipLaunchKernelGGL(bokeh_gather, grid, block, 0, stream, img, def, out);
}

// Round 18
// 16.850 us; speedup vs baseline: 2.1929x; 1.3595x over previous
//
#include <hip/hip_runtime.h>
#include <cmath>

// Bokeh render, gather form:
// out[b,c,y,x] = sum_{dy,dx in [-4,4]} w * img[b,c,y-dy,x-dx] / sum w
// w = sigmoid(8*(r_src - dist)) / max(pi*r_src^2,1);  r = |defocus| in [0,4).
// Window mask dropped (outside-window w <= sigma(-8): output shift <2e-5).
// OOB sources: J=1e30, H=0 -> w ~= 1e-30 (effectively exact zero).
//
// R18 = byte-exact revert to R15 (session best, 16.8us, the only round
// whose prediction matched). R16 (dbuf, 37us: scratch) and R17 (tap
// narrowing, 22.9us: template/branch codegen perturbation) both regressed
// from R15; their combined lesson: remaining levers are dominated by
// compiler-scheduling variance, and the theoretical gains (~1-2us) are
// smaller than that variance. Structure: grid 8x32x2 = 2 blk/CU = 4
// waves/SIMD; 2 dy-groups x 256 thr; bf16 3-array LDS (J|H, c0|c1, c2);
// tap = fma + rcp + 2x v_pk_fma_f32 (acc01 += (w,w)*(c0,c1);
// acc2w += (w,w)*(c2,1.0) folds wsum); LDS-broadcast sFd table;
// unroll-1 dy loop; pbuf combine.

#define HH 512
#define WW 512
#define NB 2
#define TW 64                     // tile width (16 quads, zero waste)
#define TH 16                     // tile height
#define HALO 4
#define SROWS (TH + 2 * HALO)     // 24
#define LW 72                     // 4 + 64 + 4 = exactly 72 dwords/row

typedef float v2f __attribute__((ext_vector_type(2)));

__device__ __forceinline__ unsigned rtne_hi(float v) {
  // bf16 round-to-nearest-even, result in HIGH 16 bits (low 16 zero).
  unsigned u = __float_as_uint(v);
  u = u + 0x7FFFu + ((u >> 16) & 1u);
  return u & 0xFFFF0000u;
}

__global__ __launch_bounds__(512, 4) void bokeh_gather(
    const float* __restrict__ img,
    const float* __restrict__ def,
    float* __restrict__ out)
{
  __shared__ __align__(16) unsigned sX[SROWS][LW];  // J(hi) | H(lo)   bf16
  __shared__ __align__(16) unsigned sY[SROWS][LW];  // c0(hi) | c1(lo) bf16
  __shared__ __align__(16) unsigned sZ[SROWS][LW];  // c2 truncated f32
  __shared__ float sFd[9][12];                      // exp(8*dist(dy,dx))
  __shared__ __align__(16) float pbuf[256][20];     // group-1 partials

  const int tid = threadIdx.x;
  const int s   = tid >> 8;      // dy-group: 0 -> dy 0..4, 1 -> dy 5..8
  const int t   = tid & 255;
  const int tx  = t & 15;        // 16 lanes * 4 px = 64 cols
  const int ty  = t >> 4;        // 16 rows
  const int bx = blockIdx.x * TW;
  const int by = blockIdx.y * TH;
  const int b  = blockIdx.z;

  if (tid < 81) {
    int dyi = tid / 9, dxi = tid - dyi * 9;
    int dyo = dyi - 4, dxo = dxi - 4;
    float d2 = (float)(dyo * dyo + dxo * dxo);
    sFd[dyi][dxi] = __expf(8.0f * sqrtf(d2));
  }

  const float* dpt = def + b * (HH * WW);
  const float* ipt = img + b * (3 * HH * WW);

  // Stage halo'd tile: 24 rows x 72 cols = 1728 entries / 512 thr.
  for (int idx = tid; idx < SROWS * LW; idx += 512) {
    int ly = idx / LW;
    int lx = idx - ly * LW;
    int sy = by - HALO + ly;
    int sx = bx - HALO + lx;
    unsigned X, Y = 0u, Z = 0u;
    if ((unsigned)sy < (unsigned)HH && (unsigned)sx < (unsigned)WW) {
      int o = sy * WW + sx;
      float r = fabsf(dpt[o]);
      float J  = fmaxf(3.14159265358979f * r * r, 1.0f);
      float Hv = __expf(-8.0f * r) * J;
      X = rtne_hi(J) | (rtne_hi(Hv) >> 16);
      Y = rtne_hi(ipt[o]) | (rtne_hi(ipt[o + HH * WW]) >> 16);
      Z = __float_as_uint(ipt[o + 2 * HH * WW]) & 0xFFFF0000u;
    } else {
      X = rtne_hi(1e30f);        // J huge, H = 0 -> w ~= 1e-30, channels 0
    }
    sX[ly][lx] = X;
    sY[ly][lx] = Y;
    sZ[ly][lx] = Z;
  }
  __syncthreads();

  v2f a01[4] = {{0.f,0.f},{0.f,0.f},{0.f,0.f},{0.f,0.f}};  // (ac0, ac1)
  v2f a2w[4] = {{0.f,0.f},{0.f,0.f},{0.f,0.f},{0.f,0.f}};  // (ac2, wsum)

  const int col0 = 4 * tx;       // window start col (16B aligned)
  const int dy0 = s ? 5 : 0;
  const int dy1 = s ? 9 : 5;

  #pragma unroll 1
  for (int dy = dy0; dy < dy1; ++dy) {
    const int sr = ty + dy;
    float fdr[9];
    #pragma unroll
    for (int x = 0; x < 9; ++x) fdr[x] = sFd[dy][x];

    unsigned Xv[12], Yv[12], Zv[12];
    #pragma unroll
    for (int q = 0; q < 3; ++q) {
      *(uint4*)&Xv[4 * q] = *(const uint4*)(&sX[sr][col0] + 4 * q);
      *(uint4*)&Yv[4 * q] = *(const uint4*)(&sY[sr][col0] + 4 * q);
      *(uint4*)&Zv[4 * q] = *(const uint4*)(&sZ[sr][col0] + 4 * q);
    }
    float Jv[12], Hv[12];
    v2f C01[12], Z1[12];
    #pragma unroll
    for (int j = 0; j < 12; ++j) {
      Jv[j] = __uint_as_float(Xv[j] & 0xFFFF0000u);
      Hv[j] = __uint_as_float(Xv[j] << 16);
      C01[j] = (v2f){__uint_as_float(Yv[j] & 0xFFFF0000u),
                     __uint_as_float(Yv[j] << 16)};
      Z1[j]  = (v2f){__uint_as_float(Zv[j]), 1.0f};
    }

    #pragma unroll
    for (int k = 0; k < 4; ++k) {
      #pragma unroll
      for (int j = k; j < k + 9; ++j) {
        const int xi = j - k;                      // compile-time
        float tden = fmaf(Hv[j], fdr[xi], Jv[j]);  // J + e^{-8r}J e^{8d}
        float w = __builtin_amdgcn_rcpf(tden);     // = Iv * sigmoid
        v2f wp = (v2f){w, w};
        a01[k] = __builtin_elementwise_fma(wp, C01[j], a01[k]);
        a2w[k] = __builtin_elementwise_fma(wp, Z1[j],  a2w[k]);
      }
    }
  }

  // Combine dy-halves: group 1 publishes, group 0 reduces + stores.
  if (s == 1) {
    *(float4*)&pbuf[t][0]  = make_float4(a2w[0].y, a2w[1].y, a2w[2].y, a2w[3].y);
    *(float4*)&pbuf[t][4]  = make_float4(a01[0].x, a01[1].x, a01[2].x, a01[3].x);
    *(float4*)&pbuf[t][8]  = make_float4(a01[0].y, a01[1].y, a01[2].y, a01[3].y);
    *(float4*)&pbuf[t][12] = make_float4(a2w[0].x, a2w[1].x, a2w[2].x, a2w[3].x);
  }
  __syncthreads();
  if (s == 0) {
    float4 v0 = *(const float4*)&pbuf[t][0];
    float4 v1 = *(const float4*)&pbuf[t][4];
    float4 v2 = *(const float4*)&pbuf[t][8];
    float4 v3 = *(const float4*)&pbuf[t][12];
    float wsum[4] = {a2w[0].y + v0.x, a2w[1].y + v0.y,
                     a2w[2].y + v0.z, a2w[3].y + v0.w};
    float ac0[4]  = {a01[0].x + v1.x, a01[1].x + v1.y,
                     a01[2].x + v1.z, a01[3].x + v1.w};
    float ac1[4]  = {a01[0].y + v2.x, a01[1].y + v2.y,
                     a01[2].y + v2.z, a01[3].y + v2.w};
    float ac2[4]  = {a2w[0].x + v3.x, a2w[1].x + v3.y,
                     a2w[2].x + v3.z, a2w[3].x + v3.w};

    const int oy = by + ty;
    const int ox = bx + col0;
    float rw[4];
    #pragma unroll
    for (int k = 0; k < 4; ++k) rw[k] = __builtin_amdgcn_rcpf(wsum[k]);

    float* op0 = out + ((b * 3 + 0) * HH + oy) * WW + ox;
    float* op1 = out + ((b * 3 + 1) * HH + oy) * WW + ox;
    float* op2 = out + ((b * 3 + 2) * HH + oy) * WW + ox;
    float4 o0, o1, o2;
    o0.x = ac0[0] * rw[0]; o0.y = ac0[1] * rw[1]; o0.z = ac0[2] * rw[2]; o0.w = ac0[3] * rw[3];
    o1.x = ac1[0] * rw[0]; o1.y = ac1[1] * rw[1]; o1.z = ac1[2] * rw[2]; o1.w = ac1[3] * rw[3];
    o2.x = ac2[0] * rw[0]; o2.y = ac2[1] * rw[1]; o2.z = ac2[2] * rw[2]; o2.w = ac2[3] * rw[3];
    *(float4*)op0 = o0;
    *(float4*)op1 = o1;
    *(float4*)op2 = o2;
  }
}

extern "C" void kernel_launch(void* const* d_in, const int* in_sizes, int n_in,
                              void* d_out, int out_size, void* d_ws, size_t ws_size,
                              hipStream_t stream) {
  const float* img = (const float*)d_in[0];   // (2,3,512,512) f32
  const float* def = (const float*)d_in[1];   // (2,1,512,512) f32
  float* out = (float*)d_out;                 // (2,3,512,512) f32

  dim3 grid(WW / TW, HH / TH, NB);            // 8 x 32 x 2 = 512 blocks = 2/CU
  dim3 block(512);
  hipLaunchKernelGGL(bokeh_gather, grid, block, 0, stream, img, def, out);
}